// Round 2
// baseline (342.150 us; speedup 1.0000x reference)
//
#include <hip/hip_runtime.h>
#include <math.h>

#define Hn 6
#define Bn 512
#define Dn 2048
#define Cn 1000
#define TAUv 0.5f

// ---------------- batched fp32 GEMM: logits[h] = feats[h] @ W[h] + b[h] ----------------
// Tile: 128(M) x 64(N), K-tile 16, 256 threads, 8x4 acc per thread.
// Per k-step: 32 FMA (64 cyc/wave) vs 3 ds_read_b128 -> FMA-issue dominated.
#define TM 128
#define TN 64
#define TK 16

__global__ __launch_bounds__(256) void gemm_logits_k(
    const float* __restrict__ feats, const float* __restrict__ Wt,
    const float* __restrict__ bias, float* __restrict__ logits)
{
  const int h  = blockIdx.z;
  const int m0 = blockIdx.y * TM;
  const int n0 = blockIdx.x * TN;
  const float* A  = feats + (size_t)h * Bn * Dn;   // [B][D] row-major
  const float* Bm = Wt    + (size_t)h * Dn * Cn;   // [D][C] row-major

  __shared__ float As[TK][TM];   // transposed A tile: As[k][m]  (8 KB)
  __shared__ float Bs[TK][TN];   // Bs[k][n]                      (4 KB)

  const int t   = threadIdx.x;
  // A staging: each thread loads 8 consecutive K floats (2x float4) of one M-row.
  // Transpose-write: bank = a_m % 32, 2 lanes share a_m (t&1) -> 2-way = free.
  const int a_m = t >> 1;              // 0..127
  const int a_k = (t & 1) << 3;        // 0 or 8
  // B staging: 1 float4 per thread.
  const int b_k = t >> 4;              // 0..15
  const int b_n = (t & 15) << 2;       // 0..60

  const int tx = t & 15, ty = t >> 4;
  const int mm = ty << 3;              // 0..120 (8 rows)
  const int nn = tx << 2;              // 0..60  (4 cols)

  float acc[8][4];
#pragma unroll
  for (int i = 0; i < 8; ++i)
#pragma unroll
    for (int j = 0; j < 4; ++j) acc[i][j] = 0.f;

  const float* a_ptr = A + (size_t)(m0 + a_m) * Dn + a_k;

  for (int k0 = 0; k0 < Dn; k0 += TK) {
    const float4 av0 = *(const float4*)(a_ptr + k0);
    const float4 av1 = *(const float4*)(a_ptr + k0 + 4);
    float4 bv;
    const int bn_g = n0 + b_n;
    if (bn_g + 3 < Cn) {
      bv = *(const float4*)(Bm + (size_t)(k0 + b_k) * Cn + bn_g);
    } else {
      const float* src = Bm + (size_t)(k0 + b_k) * Cn;
      bv.x = (bn_g + 0 < Cn) ? src[bn_g + 0] : 0.f;
      bv.y = (bn_g + 1 < Cn) ? src[bn_g + 1] : 0.f;
      bv.z = (bn_g + 2 < Cn) ? src[bn_g + 2] : 0.f;
      bv.w = (bn_g + 3 < Cn) ? src[bn_g + 3] : 0.f;
    }
    __syncthreads();   // previous iteration's compute done before overwrite
    As[a_k + 0][a_m] = av0.x;
    As[a_k + 1][a_m] = av0.y;
    As[a_k + 2][a_m] = av0.z;
    As[a_k + 3][a_m] = av0.w;
    As[a_k + 4][a_m] = av1.x;
    As[a_k + 5][a_m] = av1.y;
    As[a_k + 6][a_m] = av1.z;
    As[a_k + 7][a_m] = av1.w;
    *(float4*)(&Bs[b_k][b_n]) = bv;
    __syncthreads();

#pragma unroll
    for (int k = 0; k < TK; ++k) {
      const float4 a0 = *(const float4*)(&As[k][mm]);
      const float4 a1 = *(const float4*)(&As[k][mm + 4]);
      const float4 bf = *(const float4*)(&Bs[k][nn]);
      const float ar[8] = {a0.x, a0.y, a0.z, a0.w, a1.x, a1.y, a1.z, a1.w};
      const float br[4] = {bf.x, bf.y, bf.z, bf.w};
#pragma unroll
      for (int i = 0; i < 8; ++i)
#pragma unroll
        for (int j = 0; j < 4; ++j)
          acc[i][j] = fmaf(ar[i], br[j], acc[i][j]);
    }
  }

  // epilogue: + bias, store
  float bl[4];
#pragma unroll
  for (int j = 0; j < 4; ++j) {
    const int n = n0 + nn + j;
    bl[j] = (n < Cn) ? bias[(size_t)h * Cn + n] : 0.f;
  }
  const int n_g = n0 + nn;
#pragma unroll
  for (int i = 0; i < 8; ++i) {
    const int m = m0 + mm + i;
    float* dst = logits + (size_t)h * Bn * Cn + (size_t)m * Cn;
    if (n_g + 3 < Cn) {
      float4 ov;
      ov.x = acc[i][0] + bl[0];
      ov.y = acc[i][1] + bl[1];
      ov.z = acc[i][2] + bl[2];
      ov.w = acc[i][3] + bl[3];
      *(float4*)(dst + n_g) = ov;
    } else {
#pragma unroll
      for (int j = 0; j < 4; ++j) {
        const int n = n_g + j;
        if (n < Cn) dst[n] = acc[i][j] + bl[j];
      }
    }
  }
}

// ---------------- fused per-sample confidence (all heads) + routing ----------------
__global__ __launch_bounds__(256) void confroute_k(const float* __restrict__ logits,
                                                   float* __restrict__ out_exit,
                                                   int* __restrict__ exidx,
                                                   float* __restrict__ out_scalars)
{
  const int b = blockIdx.x;
  const int t = threadIdx.x;
  __shared__ float red[4];
  __shared__ float red2[4];
  __shared__ float mshared;
  __shared__ float confs[Hn];

  // zero the loss/acc accumulators (pick_k atomically adds into them later;
  // stream order guarantees this kernel finishes first)
  if (b == 0 && t == 0) { out_scalars[0] = 0.f; out_scalars[1] = 0.f; }

  for (int h = 0; h < Hn; ++h) {
    const float* row = logits + ((size_t)h * Bn + b) * Cn;

    float vmax = -3.4e38f;
    for (int c = t; c < Cn; c += 256) vmax = fmaxf(vmax, row[c]);
#pragma unroll
    for (int off = 32; off >= 1; off >>= 1) vmax = fmaxf(vmax, __shfl_down(vmax, off));
    if ((t & 63) == 0) red[t >> 6] = vmax;
    __syncthreads();
    if (t == 0) mshared = fmaxf(fmaxf(red[0], red[1]), fmaxf(red[2], red[3]));
    __syncthreads();
    const float m = mshared;

    float s = 0.f;
    for (int c = t; c < Cn; c += 256) s += expf(row[c] - m);
#pragma unroll
    for (int off = 32; off >= 1; off >>= 1) s += __shfl_down(s, off);
    if ((t & 63) == 0) red2[t >> 6] = s;
    __syncthreads();
    if (t == 0) {
      const float st = red2[0] + red2[1] + red2[2] + red2[3];
      confs[h] = 1.0f / st;   // max softmax prob
    }
    __syncthreads();
  }

  if (t == 0) {
    int first = -1;
    float bestc = -3.4e38f;
    int best = 0;
#pragma unroll
    for (int h = 0; h < Hn; ++h) {
      const float c = confs[h];
      if (first < 0 && c >= TAUv) first = h;
      if (c > bestc) { bestc = c; best = h; }   // strict > keeps first occurrence
    }
    const int ex = (first >= 0) ? first : best;
    exidx[b] = ex;
    out_exit[b] = (float)ex;
  }
}

// ---------------- gather chosen rows + CE loss + accuracy (atomic mean) ----------------
__global__ __launch_bounds__(256) void pick_k(
    const float* __restrict__ logits, const int* __restrict__ exidx,
    const int* __restrict__ y, float* __restrict__ out,
    float* __restrict__ out_scalars)
{
  const int b = blockIdx.x;
  const int ex = exidx[b];
  const float* row = logits + ((size_t)ex * Bn + b) * Cn;
  const int t = threadIdx.x;

  float vmax = -3.4e38f; int imax = Cn;
  for (int c = t; c < Cn; c += 256) {
    const float v = row[c];
    out[(size_t)b * Cn + c] = v;
    if (v > vmax || (v == vmax && c < imax)) { vmax = v; imax = c; }
  }
#pragma unroll
  for (int off = 32; off >= 1; off >>= 1) {
    const float ov = __shfl_down(vmax, off);
    const int   oi = __shfl_down(imax, off);
    if (ov > vmax || (ov == vmax && oi < imax)) { vmax = ov; imax = oi; }
  }
  __shared__ float rm[4]; __shared__ int ri[4];
  if ((t & 63) == 0) { rm[t >> 6] = vmax; ri[t >> 6] = imax; }
  __syncthreads();
  __shared__ float gm; __shared__ int gi;
  if (t == 0) {
    float bm = rm[0]; int bi = ri[0];
    for (int w = 1; w < 4; ++w)
      if (rm[w] > bm || (rm[w] == bm && ri[w] < bi)) { bm = rm[w]; bi = ri[w]; }
    gm = bm; gi = bi;
  }
  __syncthreads();
  const float m = gm;

  float s = 0.f;
  for (int c = t; c < Cn; c += 256) s += expf(row[c] - m);
#pragma unroll
  for (int off = 32; off >= 1; off >>= 1) s += __shfl_down(s, off);
  __shared__ float rs[4];
  if ((t & 63) == 0) rs[t >> 6] = s;
  __syncthreads();
  if (t == 0) {
    const float st = rs[0] + rs[1] + rs[2] + rs[3];
    const int yt = y[b];
    const float lp = row[yt] - m - logf(st);
    atomicAdd(&out_scalars[0], -lp * (1.0f / (float)Bn));
    atomicAdd(&out_scalars[1], ((gi == yt) ? 1.f : 0.f) * (1.0f / (float)Bn));
  }
}

extern "C" void kernel_launch(void* const* d_in, const int* in_sizes, int n_in,
                              void* d_out, int out_size, void* d_ws, size_t ws_size,
                              hipStream_t stream) {
  const float* feats = (const float*)d_in[0];   // [H,B,D]
  const float* W     = (const float*)d_in[1];   // [H,D,C]
  const float* bias  = (const float*)d_in[2];   // [H,C]
  const int*   y     = (const int*)d_in[3];     // [B]
  float* out = (float*)d_out;                   // [B*C | B | 1 | 1]

  float* logits = (float*)d_ws;                 // H*B*C
  int*   exidx  = (int*)(logits + (size_t)Hn * Bn * Cn);   // B

  float* out_exit    = out + (size_t)Bn * Cn;
  float* out_scalars = out + (size_t)Bn * Cn + Bn;

  dim3 g1((Cn + TN - 1) / TN, Bn / TM, Hn);   // 16 x 4 x 6 = 384 blocks
  gemm_logits_k<<<g1, 256, 0, stream>>>(feats, W, bias, logits);
  confroute_k<<<Bn, 256, 0, stream>>>(logits, out_exit, exidx, out_scalars);
  pick_k<<<Bn, 256, 0, stream>>>(logits, exidx, y, out, out_scalars);
}

// Round 3
// 238.192 us; speedup vs baseline: 1.4364x; 1.4364x over previous
//
#include <hip/hip_runtime.h>
#include <math.h>

#define Hn 6
#define Bn 512
#define Dn 2048
#define Cn 1000
#define TAUv 0.5f
#define KT 32

typedef __attribute__((ext_vector_type(8))) short short8;
typedef __attribute__((ext_vector_type(4))) float f32x4;

union FragU { unsigned d[4]; short8 s; };

// dword = top16(u0) | top16(u1)<<16   (u0 -> low half)
__device__ __forceinline__ unsigned pack_hi2(unsigned u0, unsigned u1) {
  return __builtin_amdgcn_perm(u1, u0, 0x07060302u);
}

// ============ split-bf16 MFMA GEMM: logits[h] = feats[h] @ W[h] + b[h] ============
// Block tile 128(M)x128(N), 512 threads = 8 waves, wave tile 32x64.
// x = hi + lo (bf16 truncate + bf16 residual); A*B ~= Ah*Bh + Ah*Bl + Al*Bh.
__global__ __launch_bounds__(512, 2) void gemm_k(
    const float* __restrict__ feats, const float* __restrict__ Wg,
    const float* __restrict__ bias, float* __restrict__ logits,
    float* __restrict__ scalars)
{
  const int h  = blockIdx.z;
  const int m0 = blockIdx.y * 128;
  const int n0 = blockIdx.x * 128;
  // zero loss/acc accumulators (head_k, launched after, atomically adds)
  if (blockIdx.x == 0 && blockIdx.y == 0 && blockIdx.z == 0 && threadIdx.x == 0) {
    scalars[0] = 0.f; scalars[1] = 0.f;
  }

  const float* A  = feats + (size_t)h * Bn * Dn;   // [B][D]
  const float* Bg = Wg    + (size_t)h * Dn * Cn;   // [D][C]

  // A: k-chunk-blocked [chunk c][m][8] -> frag read = 1 aligned b128, 2-way banks (free)
  __shared__ __align__(16) short Ah[4][128][8];
  __shared__ __align__(16) short Al[4][128][8];
  // B: transposed [n][k], row stride 34 bf16 (17 dwords, odd -> spread banks)
  __shared__ __align__(16) short Bh[128][34];
  __shared__ __align__(16) short Bl[128][34];

  const int t = threadIdx.x;
  // A staging: thread -> (m = t>>2, chunk c = t&3), loads 8 consecutive k
  const int am = t >> 2, ac = t & 3;
  // B staging: thread -> (n4 = (t&31)*4, k-pair rows bk0, bk0+1)
  const int bn4 = (t & 31) << 2, bk0 = (t >> 5) << 1;

  const int lane = t & 63;
  const int w    = t >> 6;
  const int wm   = (w & 3) * 32;    // wave m-offset (4 stripes)
  const int wn   = (w >> 2) * 64;   // wave n-offset (2 stripes)
  const int fl   = lane & 15;
  const int fq   = lane >> 4;

  f32x4 acc[2][4];
#pragma unroll
  for (int i = 0; i < 2; ++i)
#pragma unroll
    for (int j = 0; j < 4; ++j) acc[i][j] = (f32x4){0.f, 0.f, 0.f, 0.f};

  const float* aptr = A + (size_t)(m0 + am) * Dn + ac * 8;
  const bool bvalid = (n0 + bn4) < Cn;              // Cn%4==0, bn4%4==0 -> whole float4 valid
  const float* bptr = Bg + (size_t)bk0 * Cn + n0 + bn4;

  for (int kb = 0; kb < Dn; kb += KT) {
    const float4 av0 = *(const float4*)(aptr + kb);
    const float4 av1 = *(const float4*)(aptr + kb + 4);
    float4 bv0 = make_float4(0.f, 0.f, 0.f, 0.f), bv1 = bv0;
    if (bvalid) {
      bv0 = *(const float4*)(bptr + (size_t)kb * Cn);
      bv1 = *(const float4*)(bptr + (size_t)kb * Cn + Cn);
    }

    __syncthreads();   // previous iteration's compute done

    // ---- A hi/lo pack ----
    {
      const float af[8] = {av0.x, av0.y, av0.z, av0.w, av1.x, av1.y, av1.z, av1.w};
      unsigned u[8], hi[4], lo_u[8], lo[4];
#pragma unroll
      for (int j = 0; j < 8; ++j) {
        u[j] = __float_as_uint(af[j]);
        const float hif = __uint_as_float(u[j] & 0xFFFF0000u);
        lo_u[j] = __float_as_uint(af[j] - hif);
      }
#pragma unroll
      for (int j = 0; j < 4; ++j) {
        hi[j] = pack_hi2(u[2 * j], u[2 * j + 1]);
        lo[j] = pack_hi2(lo_u[2 * j], lo_u[2 * j + 1]);
      }
      *(uint4*)(&Ah[ac][am][0]) = make_uint4(hi[0], hi[1], hi[2], hi[3]);
      *(uint4*)(&Al[ac][am][0]) = make_uint4(lo[0], lo[1], lo[2], lo[3]);
    }
    // ---- B transpose + hi/lo pair-pack: dword holds (k even, k odd) for one n ----
    {
      const float f0[4] = {bv0.x, bv0.y, bv0.z, bv0.w};   // row bk0
      const float f1[4] = {bv1.x, bv1.y, bv1.z, bv1.w};   // row bk0+1
#pragma unroll
      for (int j = 0; j < 4; ++j) {
        const unsigned u0 = __float_as_uint(f0[j]);
        const unsigned u1 = __float_as_uint(f1[j]);
        const float h0 = __uint_as_float(u0 & 0xFFFF0000u);
        const float h1 = __uint_as_float(u1 & 0xFFFF0000u);
        const unsigned l0 = __float_as_uint(f0[j] - h0);
        const unsigned l1 = __float_as_uint(f1[j] - h1);
        *(unsigned*)(&Bh[bn4 + j][bk0]) = pack_hi2(u0, u1);
        *(unsigned*)(&Bl[bn4 + j][bk0]) = pack_hi2(l0, l1);
      }
    }
    __syncthreads();

    // ---- fragments + MFMA ----
    FragU ah[2], al[2];
#pragma unroll
    for (int mt = 0; mt < 2; ++mt) {
      const int m = wm + mt * 16 + fl;
      ah[mt].s = *(const short8*)(&Ah[fq][m][0]);
      al[mt].s = *(const short8*)(&Al[fq][m][0]);
    }
#pragma unroll
    for (int nt = 0; nt < 4; ++nt) {
      const int n = wn + nt * 16 + fl;
      FragU bh, bl;
      const unsigned* bhp = (const unsigned*)(&Bh[0][0]) + n * 17 + fq * 4;
      const unsigned* blp = (const unsigned*)(&Bl[0][0]) + n * 17 + fq * 4;
#pragma unroll
      for (int q = 0; q < 4; ++q) { bh.d[q] = bhp[q]; bl.d[q] = blp[q]; }
#pragma unroll
      for (int mt = 0; mt < 2; ++mt) {
        acc[mt][nt] = __builtin_amdgcn_mfma_f32_16x16x32_bf16(ah[mt].s, bh.s, acc[mt][nt], 0, 0, 0);
        acc[mt][nt] = __builtin_amdgcn_mfma_f32_16x16x32_bf16(ah[mt].s, bl.s, acc[mt][nt], 0, 0, 0);
        acc[mt][nt] = __builtin_amdgcn_mfma_f32_16x16x32_bf16(al[mt].s, bh.s, acc[mt][nt], 0, 0, 0);
      }
    }
  }

  // ---- epilogue: + bias, store (C/D: col=lane&15, row=quad*4+reg) ----
#pragma unroll
  for (int nt = 0; nt < 4; ++nt) {
    const int col = n0 + wn + nt * 16 + fl;
    if (col >= Cn) continue;
    const float bv = bias[(size_t)h * Cn + col];
#pragma unroll
    for (int mt = 0; mt < 2; ++mt) {
      const int rbase = m0 + wm + mt * 16 + fq * 4;
#pragma unroll
      for (int r = 0; r < 4; ++r) {
        logits[((size_t)h * Bn + rbase + r) * Cn + col] = acc[mt][nt][r] + bv;
      }
    }
  }
}

// ============ fused conf + route + gather + CE + acc (one block per sample) ============
__global__ __launch_bounds__(256) void head_k(
    const float* __restrict__ logits, const int* __restrict__ y,
    float* __restrict__ out, float* __restrict__ out_exit,
    float* __restrict__ scalars)
{
  const int b = blockIdx.x;
  const int t = threadIdx.x;
  const int lane = t & 63, w = t >> 6;

  float rv[Hn][4];
#pragma unroll
  for (int h = 0; h < Hn; ++h)
#pragma unroll
    for (int i = 0; i < 4; ++i) {
      const int c = t + i * 256;
      rv[h][i] = (c < Cn) ? logits[((size_t)h * Bn + b) * Cn + c] : -3.4e38f;
    }

  __shared__ float red[4], red2[4];
  __shared__ float ms[Hn], ss[Hn];

  for (int h = 0; h < Hn; ++h) {
    __syncthreads();   // protect red/red2 reuse
    float vmax = -3.4e38f;
#pragma unroll
    for (int i = 0; i < 4; ++i) vmax = fmaxf(vmax, rv[h][i]);
#pragma unroll
    for (int off = 32; off >= 1; off >>= 1) vmax = fmaxf(vmax, __shfl_down(vmax, off));
    if (lane == 0) red[w] = vmax;
    __syncthreads();
    if (t == 0) ms[h] = fmaxf(fmaxf(red[0], red[1]), fmaxf(red[2], red[3]));
    __syncthreads();
    const float m = ms[h];
    float s = 0.f;
#pragma unroll
    for (int i = 0; i < 4; ++i) {
      const int c = t + i * 256;
      if (c < Cn) s += expf(rv[h][i] - m);
    }
#pragma unroll
    for (int off = 32; off >= 1; off >>= 1) s += __shfl_down(s, off);
    if (lane == 0) red2[w] = s;
    __syncthreads();
    if (t == 0) ss[h] = red2[0] + red2[1] + red2[2] + red2[3];
  }
  __syncthreads();

  __shared__ int exsh;
  if (t == 0) {
    int first = -1, best = 0;
    float bestc = -3.4e38f;
#pragma unroll
    for (int h = 0; h < Hn; ++h) {
      const float c = 1.0f / ss[h];   // max softmax prob
      if (first < 0 && c >= TAUv) first = h;
      if (c > bestc) { bestc = c; best = h; }   // strict > keeps first occurrence
    }
    const int ex = (first >= 0) ? first : best;
    exsh = ex;
    out_exit[b] = (float)ex;
  }
  __syncthreads();
  const int ex = exsh;
  const int yt = y[b];

  __shared__ float rvyt;
  float ov[4];
  float vmax = -3.4e38f; int imax = Cn;
#pragma unroll
  for (int i = 0; i < 4; ++i) {
    float v = -3.4e38f;
#pragma unroll
    for (int h = 0; h < Hn; ++h) v = (h == ex) ? rv[h][i] : v;   // cndmask chain, no scratch
    ov[i] = v;
    const int c = t + i * 256;
    if (c < Cn) {
      out[(size_t)b * Cn + c] = v;
      if (v > vmax) { vmax = v; imax = c; }   // ascending i -> first-max kept
      if (c == yt) rvyt = v;
    }
  }
#pragma unroll
  for (int off = 32; off >= 1; off >>= 1) {
    const float ovv = __shfl_down(vmax, off);
    const int   oi  = __shfl_down(imax, off);
    if (ovv > vmax || (ovv == vmax && oi < imax)) { vmax = ovv; imax = oi; }
  }
  __shared__ float rm[4]; __shared__ int ri[4];
  if (lane == 0) { rm[w] = vmax; ri[w] = imax; }
  __syncthreads();
  if (t == 0) {
    float bm = rm[0]; int bi = ri[0];
    for (int q = 1; q < 4; ++q)
      if (rm[q] > bm || (rm[q] == bm && ri[q] < bi)) { bm = rm[q]; bi = ri[q]; }
    const float lp = rvyt - ms[ex] - logf(ss[ex]);
    atomicAdd(&scalars[0], -lp * (1.0f / (float)Bn));
    atomicAdd(&scalars[1], ((bi == yt) ? 1.f : 0.f) * (1.0f / (float)Bn));
  }
}

extern "C" void kernel_launch(void* const* d_in, const int* in_sizes, int n_in,
                              void* d_out, int out_size, void* d_ws, size_t ws_size,
                              hipStream_t stream) {
  const float* feats = (const float*)d_in[0];   // [H,B,D]
  const float* W     = (const float*)d_in[1];   // [H,D,C]
  const float* bias  = (const float*)d_in[2];   // [H,C]
  const int*   y     = (const int*)d_in[3];     // [B]
  float* out = (float*)d_out;                   // [B*C | B | 1 | 1]

  float* logits      = (float*)d_ws;            // H*B*C fp32 (12.3 MB)
  float* out_exit    = out + (size_t)Bn * Cn;
  float* out_scalars = out + (size_t)Bn * Cn + Bn;

  dim3 g1(8, 4, Hn);   // N/128 x M/128 x H = 192 blocks, 512 thr
  gemm_k<<<g1, 512, 0, stream>>>(feats, W, bias, logits, out_scalars);
  head_k<<<Bn, 256, 0, stream>>>(logits, y, out, out_exit, out_scalars);
}

// Round 4
// 199.986 us; speedup vs baseline: 1.7109x; 1.1910x over previous
//
#include <hip/hip_runtime.h>
#include <math.h>

#define Hn 6
#define Bn 512
#define Dn 2048
#define Cn 1000
#define TAUv 0.5f
#define KT 32

typedef __attribute__((ext_vector_type(8))) short short8;
typedef __attribute__((ext_vector_type(4))) float f32x4;

union FragU { unsigned d[4]; short8 s; };

// dword = top16(u0) | top16(u1)<<16   (u0 -> low half)
__device__ __forceinline__ unsigned pack_hi2(unsigned u0, unsigned u1) {
  return __builtin_amdgcn_perm(u1, u0, 0x07060302u);
}

// Convert one K-tile (fp32) to split-bf16 hi/lo and write into the given LDS buffers.
__device__ __forceinline__ void stage_tile(
    short (*AhB)[128][8], short (*AlB)[128][8],
    short (*BhB)[34], short (*BlB)[34],
    int am, int ac, int bn4, int bk0,
    float4 av0, float4 av1, float4 bv0, float4 bv1)
{
  // ---- A hi/lo pack: 8 consecutive k for row am, chunk ac ----
  {
    const float af[8] = {av0.x, av0.y, av0.z, av0.w, av1.x, av1.y, av1.z, av1.w};
    unsigned hi[4], lo[4];
#pragma unroll
    for (int j = 0; j < 4; ++j) {
      const unsigned u0 = __float_as_uint(af[2 * j]);
      const unsigned u1 = __float_as_uint(af[2 * j + 1]);
      const float h0 = __uint_as_float(u0 & 0xFFFF0000u);
      const float h1 = __uint_as_float(u1 & 0xFFFF0000u);
      const unsigned l0 = __float_as_uint(af[2 * j] - h0);
      const unsigned l1 = __float_as_uint(af[2 * j + 1] - h1);
      hi[j] = pack_hi2(u0, u1);
      lo[j] = pack_hi2(l0, l1);
    }
    *(uint4*)(&AhB[ac][am][0]) = make_uint4(hi[0], hi[1], hi[2], hi[3]);
    *(uint4*)(&AlB[ac][am][0]) = make_uint4(lo[0], lo[1], lo[2], lo[3]);
  }
  // ---- B transpose + hi/lo pair-pack: dword holds (k even, k odd) for one n ----
  {
    const float f0[4] = {bv0.x, bv0.y, bv0.z, bv0.w};   // row bk0
    const float f1[4] = {bv1.x, bv1.y, bv1.z, bv1.w};   // row bk0+1
#pragma unroll
    for (int j = 0; j < 4; ++j) {
      const unsigned u0 = __float_as_uint(f0[j]);
      const unsigned u1 = __float_as_uint(f1[j]);
      const float h0 = __uint_as_float(u0 & 0xFFFF0000u);
      const float h1 = __uint_as_float(u1 & 0xFFFF0000u);
      const unsigned l0 = __float_as_uint(f0[j] - h0);
      const unsigned l1 = __float_as_uint(f1[j] - h1);
      *(unsigned*)(&BhB[bn4 + j][bk0]) = pack_hi2(u0, u1);
      *(unsigned*)(&BlB[bn4 + j][bk0]) = pack_hi2(l0, l1);
    }
  }
}

// ============ split-bf16 MFMA GEMM, single-barrier double-buffered K-loop ============
// Block tile 128(M)x128(N), 512 threads = 8 waves, wave tile 32x64.
__global__ __launch_bounds__(512, 1) void gemm_k(
    const float* __restrict__ feats, const float* __restrict__ Wg,
    const float* __restrict__ bias, float* __restrict__ logits)
{
  const int h  = blockIdx.z;
  const int m0 = blockIdx.y * 128;
  const int n0 = blockIdx.x * 128;

  const float* A  = feats + (size_t)h * Bn * Dn;   // [B][D]
  const float* Bg = Wg    + (size_t)h * Dn * Cn;   // [D][C]

  // double-buffered LDS (67.6 KB total)
  __shared__ __align__(16) short Ah[2][4][128][8];
  __shared__ __align__(16) short Al[2][4][128][8];
  __shared__ __align__(16) short Bh[2][128][34];
  __shared__ __align__(16) short Bl[2][128][34];

  const int t = threadIdx.x;
  const int am = t >> 2, ac = t & 3;                 // A staging slot
  const int bn4 = (t & 31) << 2, bk0 = (t >> 5) << 1; // B staging slot

  const int lane = t & 63;
  const int w    = t >> 6;
  const int wm   = (w & 3) * 32;
  const int wn   = (w >> 2) * 64;
  const int fl   = lane & 15;
  const int fq   = lane >> 4;

  f32x4 acc[2][4];
#pragma unroll
  for (int i = 0; i < 2; ++i)
#pragma unroll
    for (int j = 0; j < 4; ++j) acc[i][j] = (f32x4){0.f, 0.f, 0.f, 0.f};

  const float* aptr = A + (size_t)(m0 + am) * Dn + ac * 8;
  const bool bvalid = (n0 + bn4) < Cn;
  const float* bptr = Bg + (size_t)bk0 * Cn + n0 + bn4;

  // ---- prologue: load + stage tile 0 into buffer 0 ----
  {
    const float4 av0 = *(const float4*)(aptr);
    const float4 av1 = *(const float4*)(aptr + 4);
    float4 bv0 = make_float4(0.f, 0.f, 0.f, 0.f), bv1 = bv0;
    if (bvalid) {
      bv0 = *(const float4*)(bptr);
      bv1 = *(const float4*)(bptr + Cn);
    }
    stage_tile(Ah[0], Al[0], Bh[0], Bl[0], am, ac, bn4, bk0, av0, av1, bv0, bv1);
  }

  int p = 0;
  for (int kb = 0; kb < Dn; kb += KT) {
    __syncthreads();   // buffer p's writes visible to all waves
    const int kn = kb + KT;
    const bool more = (kn < Dn);

    // issue next tile's global loads immediately (covered by MFMA phase below)
    float4 nav0, nav1, nbv0, nbv1;
    if (more) {
      nav0 = *(const float4*)(aptr + kn);
      nav1 = *(const float4*)(aptr + kn + 4);
      nbv0 = make_float4(0.f, 0.f, 0.f, 0.f); nbv1 = nbv0;
      if (bvalid) {
        nbv0 = *(const float4*)(bptr + (size_t)kn * Cn);
        nbv1 = *(const float4*)(bptr + (size_t)kn * Cn + Cn);
      }
    }

    // ---- compute from buffer p ----
    FragU ah[2], al[2];
#pragma unroll
    for (int mt = 0; mt < 2; ++mt) {
      const int m = wm + mt * 16 + fl;
      ah[mt].s = *(const short8*)(&Ah[p][fq][m][0]);
      al[mt].s = *(const short8*)(&Al[p][fq][m][0]);
    }
#pragma unroll
    for (int nt = 0; nt < 4; ++nt) {
      const int n = wn + nt * 16 + fl;
      FragU bh, bl;
      const unsigned* bhp = (const unsigned*)(&Bh[p][0][0]) + n * 17 + fq * 4;
      const unsigned* blp = (const unsigned*)(&Bl[p][0][0]) + n * 17 + fq * 4;
#pragma unroll
      for (int q = 0; q < 4; ++q) { bh.d[q] = bhp[q]; bl.d[q] = blp[q]; }
#pragma unroll
      for (int mt = 0; mt < 2; ++mt) {
        acc[mt][nt] = __builtin_amdgcn_mfma_f32_16x16x32_bf16(ah[mt].s, bh.s, acc[mt][nt], 0, 0, 0);
        acc[mt][nt] = __builtin_amdgcn_mfma_f32_16x16x32_bf16(ah[mt].s, bl.s, acc[mt][nt], 0, 0, 0);
        acc[mt][nt] = __builtin_amdgcn_mfma_f32_16x16x32_bf16(al[mt].s, bh.s, acc[mt][nt], 0, 0, 0);
      }
    }

    // ---- stage next tile into the other buffer (waits on its own loads only) ----
    if (more)
      stage_tile(Ah[p ^ 1], Al[p ^ 1], Bh[p ^ 1], Bl[p ^ 1],
                 am, ac, bn4, bk0, nav0, nav1, nbv0, nbv1);
    p ^= 1;
  }

  // ---- epilogue: + bias, store (C/D: col=lane&15, row=quad*4+reg) ----
#pragma unroll
  for (int nt = 0; nt < 4; ++nt) {
    const int col = n0 + wn + nt * 16 + fl;
    if (col >= Cn) continue;
    const float bv = bias[(size_t)h * Cn + col];
#pragma unroll
    for (int mt = 0; mt < 2; ++mt) {
      const int rbase = m0 + wm + mt * 16 + fq * 4;
#pragma unroll
      for (int r = 0; r < 4; ++r) {
        logits[((size_t)h * Bn + rbase + r) * Cn + col] = acc[mt][nt][r] + bv;
      }
    }
  }
}

// ============ per-row softmax stats: one wave per (h,b) row ============
__global__ __launch_bounds__(256) void conf_k(const float* __restrict__ logits,
                                              float* __restrict__ ms,
                                              float* __restrict__ ss,
                                              float* __restrict__ scalars)
{
  if (blockIdx.x == 0 && threadIdx.x == 0) { scalars[0] = 0.f; scalars[1] = 0.f; }
  const int w = threadIdx.x >> 6, lane = threadIdx.x & 63;
  const int r = blockIdx.x * 4 + w;                 // row = h*Bn + b
  const float* row = logits + (size_t)r * Cn;

  float vv[16];
#pragma unroll
  for (int i = 0; i < 4; ++i) {
    const int c4 = i * 256 + lane * 4;
    if (c4 + 3 < Cn) {
      const float4 v = *(const float4*)(row + c4);
      vv[4 * i] = v.x; vv[4 * i + 1] = v.y; vv[4 * i + 2] = v.z; vv[4 * i + 3] = v.w;
    } else {
#pragma unroll
      for (int j = 0; j < 4; ++j)
        vv[4 * i + j] = (c4 + j < Cn) ? row[c4 + j] : -3.4e38f;
    }
  }
  float m = -3.4e38f;
#pragma unroll
  for (int i = 0; i < 16; ++i) m = fmaxf(m, vv[i]);
#pragma unroll
  for (int off = 32; off >= 1; off >>= 1) m = fmaxf(m, __shfl_xor(m, off));
  float s = 0.f;
#pragma unroll
  for (int i = 0; i < 16; ++i) s += (vv[i] > -3.0e38f) ? expf(vv[i] - m) : 0.f;
#pragma unroll
  for (int off = 32; off >= 1; off >>= 1) s += __shfl_xor(s, off);
  if (lane == 0) { ms[r] = m; ss[r] = s; }
}

// ============ route + gather + argmax + CE (one block per sample) ============
__global__ __launch_bounds__(256) void pick_k(
    const float* __restrict__ logits, const float* __restrict__ ms,
    const float* __restrict__ ss, const int* __restrict__ y,
    float* __restrict__ out, float* __restrict__ out_exit,
    float* __restrict__ scalars)
{
  const int b = blockIdx.x, t = threadIdx.x;

  // route (uniform across block; 6 cached scalar loads)
  int first = -1, best = 0;
  float bestc = -3.4e38f;
#pragma unroll
  for (int h = 0; h < Hn; ++h) {
    const float c = 1.0f / ss[h * Bn + b];          // max softmax prob
    if (first < 0 && c >= TAUv) first = h;
    if (c > bestc) { bestc = c; best = h; }         // strict > keeps first occurrence
  }
  const int ex = (first >= 0) ? first : best;
  const float* row = logits + ((size_t)ex * Bn + b) * Cn;

  const int c4 = t * 4;
  float vv[4] = {-3.4e38f, -3.4e38f, -3.4e38f, -3.4e38f};
  if (c4 + 3 < Cn) {
    const float4 v = *(const float4*)(row + c4);
    vv[0] = v.x; vv[1] = v.y; vv[2] = v.z; vv[3] = v.w;
  } else {
#pragma unroll
    for (int j = 0; j < 4; ++j) if (c4 + j < Cn) vv[j] = row[c4 + j];
  }
  float vm = -3.4e38f; int im = 1 << 30;
#pragma unroll
  for (int j = 0; j < 4; ++j) {
    const int c = c4 + j;
    if (c < Cn) {
      out[(size_t)b * Cn + c] = vv[j];
      if (vv[j] > vm) { vm = vv[j]; im = c; }       // ascending c keeps first max
    }
  }
  const int lane = t & 63, w = t >> 6;
#pragma unroll
  for (int off = 32; off >= 1; off >>= 1) {
    const float ov = __shfl_xor(vm, off);
    const int   oi = __shfl_xor(im, off);
    if (ov > vm || (ov == vm && oi < im)) { vm = ov; im = oi; }
  }
  __shared__ float rm[4]; __shared__ int ri[4];
  if (lane == 0) { rm[w] = vm; ri[w] = im; }
  __syncthreads();
  if (t == 0) {
    float bm = rm[0]; int bi = ri[0];
    for (int q = 1; q < 4; ++q)
      if (rm[q] > bm || (rm[q] == bm && ri[q] < bi)) { bm = rm[q]; bi = ri[q]; }
    const int yt = y[b];
    const float lp = row[yt] - ms[ex * Bn + b] - logf(ss[ex * Bn + b]);
    out_exit[b] = (float)ex;
    atomicAdd(&scalars[0], -lp * (1.0f / (float)Bn));
    atomicAdd(&scalars[1], ((bi == yt) ? 1.f : 0.f) * (1.0f / (float)Bn));
  }
}

extern "C" void kernel_launch(void* const* d_in, const int* in_sizes, int n_in,
                              void* d_out, int out_size, void* d_ws, size_t ws_size,
                              hipStream_t stream) {
  const float* feats = (const float*)d_in[0];   // [H,B,D]
  const float* W     = (const float*)d_in[1];   // [H,D,C]
  const float* bias  = (const float*)d_in[2];   // [H,C]
  const int*   y     = (const int*)d_in[3];     // [B]
  float* out = (float*)d_out;                   // [B*C | B | 1 | 1]

  float* logits = (float*)d_ws;                         // H*B*C fp32 (12.3 MB)
  float* ms     = logits + (size_t)Hn * Bn * Cn;        // H*B row max
  float* ss     = ms + Hn * Bn;                         // H*B sum-exp

  float* out_exit    = out + (size_t)Bn * Cn;
  float* out_scalars = out + (size_t)Bn * Cn + Bn;

  dim3 g1(8, 4, Hn);   // N/128 x M/128 x H = 192 blocks, 512 thr
  gemm_k<<<g1, 512, 0, stream>>>(feats, W, bias, logits);
  conf_k<<<(Hn * Bn) / 4, 256, 0, stream>>>(logits, ms, ss, out_scalars);
  pick_k<<<Bn, 256, 0, stream>>>(logits, ms, ss, y, out, out_exit, out_scalars);
}